// Round 1
// baseline (1388.893 us; speedup 1.0000x reference)
//
#include <hip/hip_runtime.h>
#include <hip/hip_bf16.h>
#include <stdint.h>

#define HIDDEN 4096
#define RANK   8
#define SCALING 2.0f
#define EPS    1e-8f
#define SEQ    2048
#define BATCH  2
#define NH     32
#define NKVH   8
#define HD     128
#define MROWS  (BATCH*SEQ)   // 4096
#define NQKV   6144          // 4096 q | 1024 k | 1024 v

typedef __attribute__((ext_vector_type(8))) short bf16x8;
typedef __attribute__((ext_vector_type(4))) float f32x4;

__device__ __forceinline__ void gload_lds16(const void* g, void* lds) {
  __builtin_amdgcn_global_load_lds((__attribute__((address_space(1))) void*)g,
                                   (__attribute__((address_space(3))) void*)lds,
                                   16, 0, 0);
}

__device__ __forceinline__ unsigned short f2bf(float f) {
  __hip_bfloat16 h = __float2bfloat16(f);
  return *reinterpret_cast<unsigned short*>(&h);
}

__device__ __forceinline__ void store_c(float* p, float v) { *p = v; }
__device__ __forceinline__ void store_c(__hip_bfloat16* p, float v) { *p = __float2bfloat16(v); }

// ---------------- cast x -> bf16 ----------------
__launch_bounds__(256)
__global__ void cast_kernel(const float* __restrict__ x, unsigned short* __restrict__ y) {
  const size_t i = ((size_t)blockIdx.x * 256 + threadIdx.x) * 4;
  const float4 v = *(const float4*)&x[i];
  ushort4 pk;
  pk.x = f2bf(v.x); pk.y = f2bf(v.y); pk.z = f2bf(v.z); pk.w = f2bf(v.w);
  *(ushort4*)&y[i] = pk;
}

// ---------------- DoRA W_d precompute ----------------
// One block (256 thr) per output row.
// Wd[row][j] = (W[row][j] + 2*sum_t B[row][t]*A[t][j]) * m[row]/(||row||+eps)  -> bf16
__launch_bounds__(256)
__global__ void wd_kernel(const float* __restrict__ W, const float* __restrict__ A,
                          const float* __restrict__ B, const float* __restrict__ m,
                          unsigned short* __restrict__ out) {
  const int row = blockIdx.x;
  const int tid = threadIdx.x;
  float bl[RANK];
#pragma unroll
  for (int t = 0; t < RANK; ++t) bl[t] = SCALING * B[row*RANK + t];
  float ev[16];
  float ss = 0.f;
#pragma unroll
  for (int it = 0; it < 4; ++it) {
    const int j = it*1024 + tid*4;
    const float4 wv = *(const float4*)&W[(size_t)row*HIDDEN + j];
    float e0 = wv.x, e1 = wv.y, e2 = wv.z, e3 = wv.w;
#pragma unroll
    for (int t = 0; t < RANK; ++t) {
      const float4 av = *(const float4*)&A[t*HIDDEN + j];
      e0 += bl[t]*av.x; e1 += bl[t]*av.y; e2 += bl[t]*av.z; e3 += bl[t]*av.w;
    }
    ev[it*4+0]=e0; ev[it*4+1]=e1; ev[it*4+2]=e2; ev[it*4+3]=e3;
    ss += e0*e0 + e1*e1 + e2*e2 + e3*e3;
  }
#pragma unroll
  for (int off = 32; off > 0; off >>= 1) ss += __shfl_down(ss, off, 64);
  __shared__ float wsum[4];
  if ((tid & 63) == 0) wsum[tid >> 6] = ss;
  __syncthreads();
  const float norm = sqrtf(wsum[0]+wsum[1]+wsum[2]+wsum[3]);
  const float scl = m[row] / (norm + EPS);
#pragma unroll
  for (int it = 0; it < 4; ++it) {
    const int j = it*1024 + tid*4;
    ushort4 pk;
    pk.x = f2bf(ev[it*4+0]*scl); pk.y = f2bf(ev[it*4+1]*scl);
    pk.z = f2bf(ev[it*4+2]*scl); pk.w = f2bf(ev[it*4+3]*scl);
    *(ushort4*)&out[(size_t)row*HIDDEN + j] = pk;
  }
}

// ---------------- bf16 GEMM: C[M,N] = A[M,K] * B[N,K]^T ----------------
// m97 structure: 128x128 tile, BK=64, 4 waves each 64x64 (4x4 MFMA 16x16x32),
// global_load_lds width=16 staging.
template<typename CT>
__launch_bounds__(256)
__global__ void gemm_bt(const __hip_bfloat16* __restrict__ A,
                        const __hip_bfloat16* __restrict__ B,
                        CT* __restrict__ C, const int M, const int N, const int K) {
  __shared__ __hip_bfloat16 As[128*64];
  __shared__ __hip_bfloat16 Bs[128*64];
  const int tid = threadIdx.x;
  const int w = tid >> 6, l = tid & 63;
  const int tM = blockIdx.y * 128, tN = blockIdx.x * 128;
  const int wm = (w >> 1) * 64, wn = (w & 1) * 64;
  const int lr = l >> 3;          // staging row within 8-row group
  const int lc = (l & 7) * 8;     // staging col (8 bf16 = 16B)
  const int q4 = l >> 4;          // quad
  const int ln = l & 15;
  f32x4 acc[4][4] = {};
  const __hip_bfloat16* Ab = A + (size_t)tM * K;
  const __hip_bfloat16* Bb = B + (size_t)tN * K;
  for (int k0 = 0; k0 < K; k0 += 64) {
    __syncthreads();
#pragma unroll
    for (int i = 0; i < 4; ++i) {
      const int rr = i*32 + w*8;
      gload_lds16(Ab + (size_t)(rr + lr)*K + (k0 + lc), &As[rr*64]);
      gload_lds16(Bb + (size_t)(rr + lr)*K + (k0 + lc), &Bs[rr*64]);
    }
    __syncthreads();
    const short* Ap = (const short*)As;
    const short* Bp = (const short*)Bs;
#pragma unroll
    for (int ks = 0; ks < 2; ++ks) {
      bf16x8 af[4], bff[4];
#pragma unroll
      for (int mi = 0; mi < 4; ++mi)
        af[mi] = *(const bf16x8*)&Ap[(wm + mi*16 + ln)*64 + ks*32 + q4*8];
#pragma unroll
      for (int ni = 0; ni < 4; ++ni)
        bff[ni] = *(const bf16x8*)&Bp[(wn + ni*16 + ln)*64 + ks*32 + q4*8];
#pragma unroll
      for (int mi = 0; mi < 4; ++mi)
#pragma unroll
        for (int ni = 0; ni < 4; ++ni)
          acc[mi][ni] = __builtin_amdgcn_mfma_f32_16x16x32_bf16(af[mi], bff[ni], acc[mi][ni], 0, 0, 0);
    }
  }
  const int r0 = tM + wm + q4*4;
  const int c0 = tN + wn + ln;
#pragma unroll
  for (int mi = 0; mi < 4; ++mi)
#pragma unroll
    for (int ni = 0; ni < 4; ++ni)
#pragma unroll
      for (int r = 0; r < 4; ++r)
        store_c(&C[(size_t)(r0 + mi*16 + r)*N + c0 + ni*16], acc[mi][ni][r]);
}

// ---------------- flash attention (causal, GQA) ----------------
// One block per (b, h, 64-row q-tile). 4 waves; wave w owns q rows w*16..w*16+15, full D=128.
__launch_bounds__(256)
__global__ void attn_kernel(const __hip_bfloat16* __restrict__ qkv,
                            __hip_bfloat16* __restrict__ out) {
  const int bid = blockIdx.x;
  const int qt = bid & 31;
  const int h  = (bid >> 5) & 31;
  const int b  = bid >> 10;
  const int kvh = h >> 2;
  const int tid = threadIdx.x;
  const int w = tid >> 6, l = tid & 63;
  const int q4 = l >> 4;
  const int ln = l & 15;

  __shared__ __hip_bfloat16 Qs[64*128];
  __shared__ __hip_bfloat16 Ks[64*128];
  __shared__ __hip_bfloat16 Vt[128*72];   // V transposed [d][kv], pad 72 vs 64
  __shared__ __hip_bfloat16 Ps[4][16*64]; // per-wave P tile

  const __hip_bfloat16* qb = qkv + (size_t)(b*SEQ + qt*64)*NQKV + h*HD;
  const __hip_bfloat16* kb = qkv + (size_t)(b*SEQ)*NQKV + HIDDEN + kvh*HD;
  const __hip_bfloat16* vb = qkv + (size_t)(b*SEQ)*NQKV + (HIDDEN+1024) + kvh*HD;

  // stage Q (64x128): per wave-inst 4 rows x 16 chunks
#pragma unroll
  for (int i = 0; i < 4; ++i) {
    const int rr = i*16 + w*4;
    gload_lds16(qb + (size_t)(rr + q4)*NQKV + ln*8, &Qs[rr*128]);
  }

  f32x4 o[8] = {};
  float mrow[4] = {-1e30f,-1e30f,-1e30f,-1e30f};
  float lrow[4] = {0.f,0.f,0.f,0.f};
  const float sc = 0.08838834764831845f;  // 1/sqrt(128)

  const int nkv = qt + 1;
  for (int j = 0; j < nkv; ++j) {
    __syncthreads();
    // stage K (64x128)
#pragma unroll
    for (int i = 0; i < 4; ++i) {
      const int rr = i*16 + w*4;
      gload_lds16(kb + (size_t)(j*64 + rr + q4)*NQKV + ln*8, &Ks[rr*128]);
    }
    // stage V transposed -> Vt[d][kv]
#pragma unroll
    for (int it = 0; it < 4; ++it) {
      const int chunk = it*256 + tid;
      const int kv = chunk & 63;
      const int d0 = (chunk >> 6) * 8;
      uint4 raw = *(const uint4*)(vb + (size_t)(j*64 + kv)*NQKV + d0);
      const __hip_bfloat16* pv = (const __hip_bfloat16*)&raw;
#pragma unroll
      for (int t = 0; t < 8; ++t) Vt[(d0 + t)*72 + kv] = pv[t];
    }
    __syncthreads();

    // S = Q K^T  (wave rows w*16.., kv cols 0..63)
    f32x4 s[4] = {};
    const short* Qp = (const short*)Qs;
    const short* Kp = (const short*)Ks;
#pragma unroll
    for (int ks = 0; ks < 4; ++ks) {
      bf16x8 aq = *(const bf16x8*)&Qp[(w*16 + ln)*128 + ks*32 + q4*8];
#pragma unroll
      for (int nt = 0; nt < 4; ++nt) {
        bf16x8 bk = *(const bf16x8*)&Kp[(nt*16 + ln)*128 + ks*32 + q4*8];
        s[nt] = __builtin_amdgcn_mfma_f32_16x16x32_bf16(aq, bk, s[nt], 0, 0, 0);
      }
    }

    // online softmax; row r of this lane = q row q4*4+r; col = nt*16+ln
    float p[4][4];
#pragma unroll
    for (int r = 0; r < 4; ++r) {
      float mx = mrow[r];
#pragma unroll
      for (int nt = 0; nt < 4; ++nt) {
        float v = s[nt][r] * sc;
        if (j == qt) {
          const int qrow = w*16 + q4*4 + r;
          const int kvc = nt*16 + ln;
          if (kvc > qrow) v = -1e30f;  // causal: exp -> exactly 0, same as ref's -1e9
        }
        p[r][nt] = v;
        mx = fmaxf(mx, v);
      }
#pragma unroll
      for (int d = 1; d < 16; d <<= 1) mx = fmaxf(mx, __shfl_xor(mx, d, 64));
      const float alpha = __expf(mrow[r] - mx);
      float rs = 0.f;
#pragma unroll
      for (int nt = 0; nt < 4; ++nt) { const float e = __expf(p[r][nt] - mx); p[r][nt] = e; rs += e; }
#pragma unroll
      for (int d = 1; d < 16; d <<= 1) rs += __shfl_xor(rs, d, 64);
      mrow[r] = mx;
      lrow[r] = lrow[r]*alpha + rs;
#pragma unroll
      for (int ni = 0; ni < 8; ++ni) o[ni][r] *= alpha;
    }

    // P (C-layout) -> LDS -> A-operand layout
    __hip_bfloat16* Pw = Ps[w];
#pragma unroll
    for (int r = 0; r < 4; ++r)
#pragma unroll
      for (int nt = 0; nt < 4; ++nt)
        Pw[(q4*4 + r)*64 + nt*16 + ln] = __float2bfloat16(p[r][nt]);
    __syncthreads();

    // O += P V
    const short* Pp = (const short*)Ps[w];
    const short* Vp = (const short*)Vt;
#pragma unroll
    for (int ks = 0; ks < 2; ++ks) {
      bf16x8 ap = *(const bf16x8*)&Pp[ln*64 + ks*32 + q4*8];
#pragma unroll
      for (int ni = 0; ni < 8; ++ni) {
        bf16x8 bv = *(const bf16x8*)&Vp[(ni*16 + ln)*72 + ks*32 + q4*8];
        o[ni] = __builtin_amdgcn_mfma_f32_16x16x32_bf16(ap, bv, o[ni], 0, 0, 0);
      }
    }
  }

  // epilogue: normalize, write [b*S+s][h*128+d] bf16
  const int row0 = b*SEQ + qt*64 + w*16 + q4*4;
#pragma unroll
  for (int r = 0; r < 4; ++r) {
    const float inv = 1.f / lrow[r];
#pragma unroll
    for (int ni = 0; ni < 8; ++ni)
      out[(size_t)(row0 + r)*HIDDEN + h*HD + ni*16 + ln] = __float2bfloat16(o[ni][r] * inv);
  }
}

extern "C" void kernel_launch(void* const* d_in, const int* in_sizes, int n_in,
                              void* d_out, int out_size, void* d_ws, size_t ws_size,
                              hipStream_t stream) {
  (void)in_sizes; (void)n_in; (void)out_size; (void)ws_size;
  const float* x  = (const float*)d_in[0];
  // d_in[1] attention_mask: deterministic causal -> applied analytically
  const float* Wq = (const float*)d_in[2];
  const float* Aq = (const float*)d_in[3];
  const float* Bq = (const float*)d_in[4];
  const float* mq = (const float*)d_in[5];
  const float* Wk = (const float*)d_in[6];
  const float* Ak = (const float*)d_in[7];
  const float* Bk = (const float*)d_in[8];
  const float* mk = (const float*)d_in[9];
  const float* Wv = (const float*)d_in[10];
  const float* Av = (const float*)d_in[11];
  const float* Bv = (const float*)d_in[12];
  const float* mv = (const float*)d_in[13];
  const float* Wo = (const float*)d_in[14];
  const float* Ao = (const float*)d_in[15];
  const float* Bo = (const float*)d_in[16];
  const float* mo = (const float*)d_in[17];

  char* ws = (char*)d_ws;
  // 0        .. 32MiB  : x_bf16, later reused as attn_out (bf16 [4096][4096])
  // 32MiB    .. 80MiB  : Wd_qkv bf16 [6144][4096], later reused as Wd_o [4096][4096]
  // 80MiB    .. 128MiB : qkv bf16 [4096][6144]
  __hip_bfloat16* xbf = (__hip_bfloat16*)ws;
  __hip_bfloat16* wd  = (__hip_bfloat16*)(ws + (size_t)33554432);
  __hip_bfloat16* qkv = (__hip_bfloat16*)(ws + (size_t)83886080);

  cast_kernel<<<16384, 256, 0, stream>>>(x, (unsigned short*)xbf);
  wd_kernel<<<4096, 256, 0, stream>>>(Wq, Aq, Bq, mq, (unsigned short*)wd);
  wd_kernel<<<1024, 256, 0, stream>>>(Wk, Ak, Bk, mk, (unsigned short*)(wd + (size_t)4096*4096));
  wd_kernel<<<1024, 256, 0, stream>>>(Wv, Av, Bv, mv, (unsigned short*)(wd + (size_t)5120*4096));
  gemm_bt<__hip_bfloat16><<<dim3(48, 32), 256, 0, stream>>>(xbf, wd, qkv, MROWS, NQKV, HIDDEN);
  wd_kernel<<<4096, 256, 0, stream>>>(Wo, Ao, Bo, mo, (unsigned short*)wd);   // Wd_o reuses wd buffer
  attn_kernel<<<2048, 256, 0, stream>>>(qkv, xbf);                             // attn_out reuses xbf
  gemm_bt<float><<<dim3(32, 32), 256, 0, stream>>>(xbf, wd, (float*)d_out, MROWS, HIDDEN, HIDDEN);
}

// Round 2
// 1063.255 us; speedup vs baseline: 1.3063x; 1.3063x over previous
//
#include <hip/hip_runtime.h>
#include <hip/hip_bf16.h>
#include <stdint.h>

#define HIDDEN 4096
#define RANK   8
#define SCALING 2.0f
#define EPS    1e-8f
#define SEQ    2048
#define BATCH  2
#define NH     32
#define NKVH   8
#define HD     128
#define MROWS  (BATCH*SEQ)   // 4096
#define NQKV   6144          // 4096 q | 1024 k | 1024 v

typedef __attribute__((ext_vector_type(8))) short bf16x8;
typedef __attribute__((ext_vector_type(4))) short bf16x4;
typedef __attribute__((ext_vector_type(4))) float f32x4;

__device__ __forceinline__ void gload_lds16(const void* g, void* lds) {
  __builtin_amdgcn_global_load_lds((__attribute__((address_space(1))) void*)g,
                                   (__attribute__((address_space(3))) void*)lds,
                                   16, 0, 0);
}

__device__ __forceinline__ unsigned short f2bf(float f) {
  __hip_bfloat16 h = __float2bfloat16(f);
  return *reinterpret_cast<unsigned short*>(&h);
}

__device__ __forceinline__ void store_c(float* p, float v) { *p = v; }
__device__ __forceinline__ void store_c(__hip_bfloat16* p, float v) { *p = __float2bfloat16(v); }

// 8-bf16 LDS fragment read as 2x ds_read_b64 (for padded strides where 16B
// alignment can't be guaranteed; 4-way worst-case conflicts vs 8-way for b128)
__device__ __forceinline__ bf16x8 lds_read8_b64(const short* p) {
  bf16x4 lo = *(const bf16x4*)p;
  bf16x4 hi = *(const bf16x4*)(p + 4);
  bf16x8 r;
  r[0]=lo[0]; r[1]=lo[1]; r[2]=lo[2]; r[3]=lo[3];
  r[4]=hi[0]; r[5]=hi[1]; r[6]=hi[2]; r[7]=hi[3];
  return r;
}

// ---------------- cast x -> bf16 ----------------
__launch_bounds__(256)
__global__ void cast_kernel(const float* __restrict__ x, unsigned short* __restrict__ y) {
  const size_t i = ((size_t)blockIdx.x * 256 + threadIdx.x) * 4;
  const float4 v = *(const float4*)&x[i];
  ushort4 pk;
  pk.x = f2bf(v.x); pk.y = f2bf(v.y); pk.z = f2bf(v.z); pk.w = f2bf(v.w);
  *(ushort4*)&y[i] = pk;
}

// ---------------- DoRA W_d precompute ----------------
__launch_bounds__(256)
__global__ void wd_kernel(const float* __restrict__ W, const float* __restrict__ A,
                          const float* __restrict__ B, const float* __restrict__ m,
                          unsigned short* __restrict__ out) {
  const int row = blockIdx.x;
  const int tid = threadIdx.x;
  float bl[RANK];
#pragma unroll
  for (int t = 0; t < RANK; ++t) bl[t] = SCALING * B[row*RANK + t];
  float ev[16];
  float ss = 0.f;
#pragma unroll
  for (int it = 0; it < 4; ++it) {
    const int j = it*1024 + tid*4;
    const float4 wv = *(const float4*)&W[(size_t)row*HIDDEN + j];
    float e0 = wv.x, e1 = wv.y, e2 = wv.z, e3 = wv.w;
#pragma unroll
    for (int t = 0; t < RANK; ++t) {
      const float4 av = *(const float4*)&A[t*HIDDEN + j];
      e0 += bl[t]*av.x; e1 += bl[t]*av.y; e2 += bl[t]*av.z; e3 += bl[t]*av.w;
    }
    ev[it*4+0]=e0; ev[it*4+1]=e1; ev[it*4+2]=e2; ev[it*4+3]=e3;
    ss += e0*e0 + e1*e1 + e2*e2 + e3*e3;
  }
#pragma unroll
  for (int off = 32; off > 0; off >>= 1) ss += __shfl_down(ss, off, 64);
  __shared__ float wsum[4];
  if ((tid & 63) == 0) wsum[tid >> 6] = ss;
  __syncthreads();
  const float norm = sqrtf(wsum[0]+wsum[1]+wsum[2]+wsum[3]);
  const float scl = m[row] / (norm + EPS);
#pragma unroll
  for (int it = 0; it < 4; ++it) {
    const int j = it*1024 + tid*4;
    ushort4 pk;
    pk.x = f2bf(ev[it*4+0]*scl); pk.y = f2bf(ev[it*4+1]*scl);
    pk.z = f2bf(ev[it*4+2]*scl); pk.w = f2bf(ev[it*4+3]*scl);
    *(ushort4*)&out[(size_t)row*HIDDEN + j] = pk;
  }
}

// ---------------- bf16 GEMM: C[M,N] = A[M,K] * B[N,K]^T ----------------
template<typename CT>
__launch_bounds__(256)
__global__ void gemm_bt(const __hip_bfloat16* __restrict__ A,
                        const __hip_bfloat16* __restrict__ B,
                        CT* __restrict__ C, const int M, const int N, const int K) {
  __shared__ __hip_bfloat16 As[128*64];
  __shared__ __hip_bfloat16 Bs[128*64];
  const int tid = threadIdx.x;
  const int w = tid >> 6, l = tid & 63;
  const int tM = blockIdx.y * 128, tN = blockIdx.x * 128;
  const int wm = (w >> 1) * 64, wn = (w & 1) * 64;
  const int lr = l >> 3;
  const int lc = (l & 7) * 8;
  const int q4 = l >> 4;
  const int ln = l & 15;
  f32x4 acc[4][4] = {};
  const __hip_bfloat16* Ab = A + (size_t)tM * K;
  const __hip_bfloat16* Bb = B + (size_t)tN * K;
  for (int k0 = 0; k0 < K; k0 += 64) {
    __syncthreads();
#pragma unroll
    for (int i = 0; i < 4; ++i) {
      const int rr = i*32 + w*8;
      gload_lds16(Ab + (size_t)(rr + lr)*K + (k0 + lc), &As[rr*64]);
      gload_lds16(Bb + (size_t)(rr + lr)*K + (k0 + lc), &Bs[rr*64]);
    }
    __syncthreads();
    const short* Ap = (const short*)As;
    const short* Bp = (const short*)Bs;
#pragma unroll
    for (int ks = 0; ks < 2; ++ks) {
      bf16x8 af[4], bff[4];
#pragma unroll
      for (int mi = 0; mi < 4; ++mi)
        af[mi] = *(const bf16x8*)&Ap[(wm + mi*16 + ln)*64 + ks*32 + q4*8];
#pragma unroll
      for (int ni = 0; ni < 4; ++ni)
        bff[ni] = *(const bf16x8*)&Bp[(wn + ni*16 + ln)*64 + ks*32 + q4*8];
#pragma unroll
      for (int mi = 0; mi < 4; ++mi)
#pragma unroll
        for (int ni = 0; ni < 4; ++ni)
          acc[mi][ni] = __builtin_amdgcn_mfma_f32_16x16x32_bf16(af[mi], bff[ni], acc[mi][ni], 0, 0, 0);
    }
  }
  const int r0 = tM + wm + q4*4;
  const int c0 = tN + wn + ln;
#pragma unroll
  for (int mi = 0; mi < 4; ++mi)
#pragma unroll
    for (int ni = 0; ni < 4; ++ni)
#pragma unroll
      for (int r = 0; r < 4; ++r)
        store_c(&C[(size_t)(r0 + mi*16 + r)*N + c0 + ni*16], acc[mi][ni][r]);
}

// ---------------- flash attention (causal, GQA) ----------------
// One block per (b, h, 64-row q-tile), qt descending for load balance.
// 4 waves; wave w owns q rows w*16..w*16+15 (Q frags in registers), full D=128.
// LDS: Ks 16KB + Vt(stride 68) 17KB + Ps(stride 68) 8.5KB = 42.5KB -> 3 blocks/CU.
#define VT_S 68
#define PS_S 68
__launch_bounds__(256, 3)
__global__ void attn_kernel(const __hip_bfloat16* __restrict__ qkv,
                            __hip_bfloat16* __restrict__ out) {
  const int bid = blockIdx.x;
  const int qt = 31 - (bid >> 6);      // big tiles dispatched first
  const int hb = bid & 63;
  const int h  = hb & 31;
  const int b  = hb >> 5;
  const int kvh = h >> 2;
  const int tid = threadIdx.x;
  const int w = tid >> 6, l = tid & 63;
  const int q4 = l >> 4;
  const int ln = l & 15;

  __shared__ __hip_bfloat16 Ks[64*128];
  __shared__ __hip_bfloat16 Vt[128*VT_S];    // V transposed [d][kv]
  __shared__ __hip_bfloat16 Ps[4][16*PS_S];  // per-wave P tile [q][kv]

  const __hip_bfloat16* kb = qkv + (size_t)(b*SEQ)*NQKV + HIDDEN + kvh*HD;
  const __hip_bfloat16* vb = qkv + (size_t)(b*SEQ)*NQKV + (HIDDEN+1024) + kvh*HD;

  // Q fragments in registers: wave w, lane (q4,ln) -> row w*16+ln, k = ks*32+q4*8..+7
  bf16x8 aq[4];
  {
    const __hip_bfloat16* qr = qkv + (size_t)(b*SEQ + qt*64 + w*16 + ln)*NQKV + h*HD;
#pragma unroll
    for (int ks = 0; ks < 4; ++ks) {
      uint4 raw = *(const uint4*)(qr + ks*32 + q4*8);
      aq[ks] = *(const bf16x8*)&raw;
    }
  }

  f32x4 o[8] = {};
  float mrow[4] = {-1e30f,-1e30f,-1e30f,-1e30f};
  float lrow[4] = {0.f,0.f,0.f,0.f};
  const float sc = 0.08838834764831845f;  // 1/sqrt(128)

  const int nkv = qt + 1;
  for (int j = 0; j < nkv; ++j) {
    __syncthreads();   // waves done reading Ks/Vt of previous iter
    // stage K (64x128) via async global->LDS
#pragma unroll
    for (int i = 0; i < 4; ++i) {
      const int rr = i*16 + w*4;
      gload_lds16(kb + (size_t)(j*64 + rr + q4)*NQKV + ln*8, &Ks[rr*128]);
    }
    // stage V transposed -> Vt[d][kv], stride 68 (conflict-free writes)
#pragma unroll
    for (int it = 0; it < 4; ++it) {
      const int chunk = it*256 + tid;
      const int kv = chunk & 63;
      const int d0 = (chunk >> 6) * 8;
      uint4 raw = *(const uint4*)(vb + (size_t)(j*64 + kv)*NQKV + d0);
      const __hip_bfloat16* pv = (const __hip_bfloat16*)&raw;
#pragma unroll
      for (int t = 0; t < 8; ++t) Vt[(d0 + t)*VT_S + kv] = pv[t];
    }
    __syncthreads();

    // S = Q K^T (wave's 16 q rows x 64 kv cols)
    f32x4 s[4] = {};
    const short* Kp = (const short*)Ks;
#pragma unroll
    for (int ks = 0; ks < 4; ++ks) {
#pragma unroll
      for (int nt = 0; nt < 4; ++nt) {
        bf16x8 bk = *(const bf16x8*)&Kp[(nt*16 + ln)*128 + ks*32 + q4*8];
        s[nt] = __builtin_amdgcn_mfma_f32_16x16x32_bf16(aq[ks], bk, s[nt], 0, 0, 0);
      }
    }

    // online softmax; lane's row r = q4*4+r, col = nt*16+ln
    float p[4][4];
#pragma unroll
    for (int r = 0; r < 4; ++r) {
      float mx = mrow[r];
#pragma unroll
      for (int nt = 0; nt < 4; ++nt) {
        float v = s[nt][r] * sc;
        if (j == qt) {
          const int qrow = w*16 + q4*4 + r;
          const int kvc = nt*16 + ln;
          if (kvc > qrow) v = -1e30f;
        }
        p[r][nt] = v;
        mx = fmaxf(mx, v);
      }
#pragma unroll
      for (int d = 1; d < 16; d <<= 1) mx = fmaxf(mx, __shfl_xor(mx, d, 64));
      const float alpha = __expf(mrow[r] - mx);
      float rs = 0.f;
#pragma unroll
      for (int nt = 0; nt < 4; ++nt) { const float e = __expf(p[r][nt] - mx); p[r][nt] = e; rs += e; }
#pragma unroll
      for (int d = 1; d < 16; d <<= 1) rs += __shfl_xor(rs, d, 64);
      mrow[r] = mx;
      lrow[r] = lrow[r]*alpha + rs;
#pragma unroll
      for (int ni = 0; ni < 8; ++ni) o[ni][r] *= alpha;
    }

    // P (C-layout) -> wave-private LDS tile (no barrier needed)
    __hip_bfloat16* Pw = Ps[w];
#pragma unroll
    for (int r = 0; r < 4; ++r)
#pragma unroll
      for (int nt = 0; nt < 4; ++nt)
        Pw[(q4*4 + r)*PS_S + nt*16 + ln] = __float2bfloat16(p[r][nt]);

    // O += P V
    const short* Pp = (const short*)Ps[w];
    const short* Vp = (const short*)Vt;
#pragma unroll
    for (int ks = 0; ks < 2; ++ks) {
      bf16x8 ap = lds_read8_b64(&Pp[ln*PS_S + ks*32 + q4*8]);
#pragma unroll
      for (int ni = 0; ni < 8; ++ni) {
        bf16x8 bv = lds_read8_b64(&Vp[(ni*16 + ln)*VT_S + ks*32 + q4*8]);
        o[ni] = __builtin_amdgcn_mfma_f32_16x16x32_bf16(ap, bv, o[ni], 0, 0, 0);
      }
    }
  }

  // epilogue
  const int row0 = b*SEQ + qt*64 + w*16 + q4*4;
#pragma unroll
  for (int r = 0; r < 4; ++r) {
    const float inv = 1.f / lrow[r];
#pragma unroll
    for (int ni = 0; ni < 8; ++ni)
      out[(size_t)(row0 + r)*HIDDEN + h*HD + ni*16 + ln] = __float2bfloat16(o[ni][r] * inv);
  }
}

extern "C" void kernel_launch(void* const* d_in, const int* in_sizes, int n_in,
                              void* d_out, int out_size, void* d_ws, size_t ws_size,
                              hipStream_t stream) {
  (void)in_sizes; (void)n_in; (void)out_size; (void)ws_size;
  const float* x  = (const float*)d_in[0];
  const float* Wq = (const float*)d_in[2];
  const float* Aq = (const float*)d_in[3];
  const float* Bq = (const float*)d_in[4];
  const float* mq = (const float*)d_in[5];
  const float* Wk = (const float*)d_in[6];
  const float* Ak = (const float*)d_in[7];
  const float* Bk = (const float*)d_in[8];
  const float* mk = (const float*)d_in[9];
  const float* Wv = (const float*)d_in[10];
  const float* Av = (const float*)d_in[11];
  const float* Bv = (const float*)d_in[12];
  const float* mv = (const float*)d_in[13];
  const float* Wo = (const float*)d_in[14];
  const float* Ao = (const float*)d_in[15];
  const float* Bo = (const float*)d_in[16];
  const float* mo = (const float*)d_in[17];

  char* ws = (char*)d_ws;
  __hip_bfloat16* xbf = (__hip_bfloat16*)ws;                          // 32 MiB, reused as attn_out
  __hip_bfloat16* wd  = (__hip_bfloat16*)(ws + (size_t)33554432);     // 48 MiB, reused as Wd_o
  __hip_bfloat16* qkv = (__hip_bfloat16*)(ws + (size_t)83886080);     // 48 MiB

  cast_kernel<<<16384, 256, 0, stream>>>(x, (unsigned short*)xbf);
  wd_kernel<<<4096, 256, 0, stream>>>(Wq, Aq, Bq, mq, (unsigned short*)wd);
  wd_kernel<<<1024, 256, 0, stream>>>(Wk, Ak, Bk, mk, (unsigned short*)(wd + (size_t)4096*4096));
  wd_kernel<<<1024, 256, 0, stream>>>(Wv, Av, Bv, mv, (unsigned short*)(wd + (size_t)5120*4096));
  gemm_bt<__hip_bfloat16><<<dim3(48, 32), 256, 0, stream>>>(xbf, wd, qkv, MROWS, NQKV, HIDDEN);
  wd_kernel<<<4096, 256, 0, stream>>>(Wo, Ao, Bo, mo, (unsigned short*)wd);
  attn_kernel<<<2048, 256, 0, stream>>>(qkv, xbf);
  gemm_bt<float><<<dim3(32, 32), 256, 0, stream>>>(xbf, wd, (float*)d_out, MROWS, HIDDEN, HIDDEN);
}

// Round 3
// 900.986 us; speedup vs baseline: 1.5415x; 1.1801x over previous
//
#include <hip/hip_runtime.h>
#include <hip/hip_bf16.h>
#include <stdint.h>

#define HIDDEN 4096
#define RANK   8
#define SCALING 2.0f
#define EPS    1e-8f
#define SEQ    2048
#define BATCH  2
#define NH     32
#define NKVH   8
#define HD     128
#define MROWS  (BATCH*SEQ)   // 4096
#define NQKV   6144          // 4096 q | 1024 k | 1024 v

typedef __attribute__((ext_vector_type(8))) short bf16x8;
typedef __attribute__((ext_vector_type(4))) short bf16x4;
typedef __attribute__((ext_vector_type(4))) float f32x4;

__device__ __forceinline__ void gload_lds16(const void* g, void* lds) {
  __builtin_amdgcn_global_load_lds((__attribute__((address_space(1))) void*)g,
                                   (__attribute__((address_space(3))) void*)lds,
                                   16, 0, 0);
}

__device__ __forceinline__ unsigned short f2bf(float f) {
  __hip_bfloat16 h = __float2bfloat16(f);
  return *reinterpret_cast<unsigned short*>(&h);
}

__device__ __forceinline__ void store_c(float* p, float v) { *p = v; }
__device__ __forceinline__ void store_c(__hip_bfloat16* p, float v) { *p = __float2bfloat16(v); }

__device__ __forceinline__ bf16x8 lds_read8_b64(const short* p) {
  bf16x4 lo = *(const bf16x4*)p;
  bf16x4 hi = *(const bf16x4*)(p + 4);
  bf16x8 r;
  r[0]=lo[0]; r[1]=lo[1]; r[2]=lo[2]; r[3]=lo[3];
  r[4]=hi[0]; r[5]=hi[1]; r[6]=hi[2]; r[7]=hi[3];
  return r;
}

// ---------------- cast x -> bf16 ----------------
__launch_bounds__(256)
__global__ void cast_kernel(const float* __restrict__ x, unsigned short* __restrict__ y) {
  const size_t i = ((size_t)blockIdx.x * 256 + threadIdx.x) * 4;
  const float4 v = *(const float4*)&x[i];
  ushort4 pk;
  pk.x = f2bf(v.x); pk.y = f2bf(v.y); pk.z = f2bf(v.z); pk.w = f2bf(v.w);
  *(ushort4*)&y[i] = pk;
}

// ---------------- DoRA W_d precompute ----------------
__launch_bounds__(256)
__global__ void wd_kernel(const float* __restrict__ W, const float* __restrict__ A,
                          const float* __restrict__ B, const float* __restrict__ m,
                          unsigned short* __restrict__ out) {
  const int row = blockIdx.x;
  const int tid = threadIdx.x;
  float bl[RANK];
#pragma unroll
  for (int t = 0; t < RANK; ++t) bl[t] = SCALING * B[row*RANK + t];
  float ev[16];
  float ss = 0.f;
#pragma unroll
  for (int it = 0; it < 4; ++it) {
    const int j = it*1024 + tid*4;
    const float4 wv = *(const float4*)&W[(size_t)row*HIDDEN + j];
    float e0 = wv.x, e1 = wv.y, e2 = wv.z, e3 = wv.w;
#pragma unroll
    for (int t = 0; t < RANK; ++t) {
      const float4 av = *(const float4*)&A[t*HIDDEN + j];
      e0 += bl[t]*av.x; e1 += bl[t]*av.y; e2 += bl[t]*av.z; e3 += bl[t]*av.w;
    }
    ev[it*4+0]=e0; ev[it*4+1]=e1; ev[it*4+2]=e2; ev[it*4+3]=e3;
    ss += e0*e0 + e1*e1 + e2*e2 + e3*e3;
  }
#pragma unroll
  for (int off = 32; off > 0; off >>= 1) ss += __shfl_down(ss, off, 64);
  __shared__ float wsum[4];
  if ((tid & 63) == 0) wsum[tid >> 6] = ss;
  __syncthreads();
  const float norm = sqrtf(wsum[0]+wsum[1]+wsum[2]+wsum[3]);
  const float scl = m[row] / (norm + EPS);
#pragma unroll
  for (int it = 0; it < 4; ++it) {
    const int j = it*1024 + tid*4;
    ushort4 pk;
    pk.x = f2bf(ev[it*4+0]*scl); pk.y = f2bf(ev[it*4+1]*scl);
    pk.z = f2bf(ev[it*4+2]*scl); pk.w = f2bf(ev[it*4+3]*scl);
    *(ushort4*)&out[(size_t)row*HIDDEN + j] = pk;
  }
}

// ---------------- bf16 GEMM: C[M,N] = A[M,K] * B[N,K]^T ----------------
// m97 structure + XOR chunk swizzle: chunk c of row r lives at LDS slot c^(r%8).
// Staging: lane-constant XOR on the GLOBAL source (DMA LDS side stays linear);
// fragment ds_read_b128 banks become 2-way (free) instead of 16-way.
template<typename CT>
__launch_bounds__(256)
__global__ void gemm_bt(const __hip_bfloat16* __restrict__ A,
                        const __hip_bfloat16* __restrict__ B,
                        CT* __restrict__ C, const int M, const int N, const int K) {
  __shared__ __hip_bfloat16 As[128*64];
  __shared__ __hip_bfloat16 Bs[128*64];
  const int tid = threadIdx.x;
  const int w = tid >> 6, l = tid & 63;
  const int tM = blockIdx.y * 128, tN = blockIdx.x * 128;
  const int wm = (w >> 1) * 64, wn = (w & 1) * 64;
  const int lr = l >> 3;                     // staging row within 8-row group
  const int lcs = ((l & 7) ^ lr) * 8;        // swizzled source chunk (elems)
  const int q4 = l >> 4;
  const int ln = l & 15;
  const int sw = ln & 7;                     // read-side swizzle key
  f32x4 acc[4][4] = {};
  const __hip_bfloat16* Ab = A + (size_t)tM * K;
  const __hip_bfloat16* Bb = B + (size_t)tN * K;
  for (int k0 = 0; k0 < K; k0 += 64) {
    __syncthreads();
#pragma unroll
    for (int i = 0; i < 4; ++i) {
      const int rr = i*32 + w*8;
      gload_lds16(Ab + (size_t)(rr + lr)*K + (k0 + lcs), &As[rr*64]);
      gload_lds16(Bb + (size_t)(rr + lr)*K + (k0 + lcs), &Bs[rr*64]);
    }
    __syncthreads();
    const short* Ap = (const short*)As;
    const short* Bp = (const short*)Bs;
#pragma unroll
    for (int ks = 0; ks < 2; ++ks) {
      const int slot = ((ks*4 + q4) ^ sw) * 8;
      bf16x8 af[4], bff[4];
#pragma unroll
      for (int mi = 0; mi < 4; ++mi)
        af[mi] = *(const bf16x8*)&Ap[(wm + mi*16 + ln)*64 + slot];
#pragma unroll
      for (int ni = 0; ni < 4; ++ni)
        bff[ni] = *(const bf16x8*)&Bp[(wn + ni*16 + ln)*64 + slot];
#pragma unroll
      for (int mi = 0; mi < 4; ++mi)
#pragma unroll
        for (int ni = 0; ni < 4; ++ni)
          acc[mi][ni] = __builtin_amdgcn_mfma_f32_16x16x32_bf16(af[mi], bff[ni], acc[mi][ni], 0, 0, 0);
    }
  }
  const int r0 = tM + wm + q4*4;
  const int c0 = tN + wn + ln;
#pragma unroll
  for (int mi = 0; mi < 4; ++mi)
#pragma unroll
    for (int ni = 0; ni < 4; ++ni)
#pragma unroll
      for (int r = 0; r < 4; ++r)
        store_c(&C[(size_t)(r0 + mi*16 + r)*N + c0 + ni*16], acc[mi][ni][r]);
}

// ---------------- flash attention (causal, GQA) ----------------
// Ks gets the same XOR chunk swizzle (16 chunks/row, key = row%8).
#define VT_S 68
#define PS_S 68
__launch_bounds__(256, 3)
__global__ void attn_kernel(const __hip_bfloat16* __restrict__ qkv,
                            __hip_bfloat16* __restrict__ out) {
  const int bid = blockIdx.x;
  const int qt = 31 - (bid >> 6);      // big tiles dispatched first
  const int hb = bid & 63;
  const int h  = hb & 31;
  const int b  = hb >> 5;
  const int kvh = h >> 2;
  const int tid = threadIdx.x;
  const int w = tid >> 6, l = tid & 63;
  const int q4 = l >> 4;
  const int ln = l & 15;
  const int sw = ln & 7;

  __shared__ __hip_bfloat16 Ks[64*128];
  __shared__ __hip_bfloat16 Vt[128*VT_S];
  __shared__ __hip_bfloat16 Ps[4][16*PS_S];

  const __hip_bfloat16* kb = qkv + (size_t)(b*SEQ)*NQKV + HIDDEN + kvh*HD;
  const __hip_bfloat16* vb = qkv + (size_t)(b*SEQ)*NQKV + (HIDDEN+1024) + kvh*HD;

  // K staging swizzle: lane l covers row rr + l/16, LDS slot l%16; source chunk
  // = (l%16) ^ ((row)%8) with row%8 = 4*(w&1) ^ (l>>4)  -> lane-constant.
  const int krow = l >> 4;
  const int kchunk = ((l & 15) ^ krow ^ ((w & 1) << 2)) * 8;  // elems

  // Q fragments in registers
  bf16x8 aq[4];
  {
    const __hip_bfloat16* qr = qkv + (size_t)(b*SEQ + qt*64 + w*16 + ln)*NQKV + h*HD;
#pragma unroll
    for (int ks = 0; ks < 4; ++ks) {
      uint4 raw = *(const uint4*)(qr + ks*32 + q4*8);
      aq[ks] = *(const bf16x8*)&raw;
    }
  }

  f32x4 o[8] = {};
  float mrow[4] = {-1e30f,-1e30f,-1e30f,-1e30f};
  float lrow[4] = {0.f,0.f,0.f,0.f};
  const float sc = 0.08838834764831845f;  // 1/sqrt(128)

  const int nkv = qt + 1;
  for (int j = 0; j < nkv; ++j) {
    __syncthreads();
    // stage K (64x128), swizzled
#pragma unroll
    for (int i = 0; i < 4; ++i) {
      const int rr = i*16 + w*4;
      gload_lds16(kb + (size_t)(j*64 + rr + krow)*NQKV + kchunk, &Ks[rr*128]);
    }
    // stage V transposed -> Vt[d][kv], stride 68
#pragma unroll
    for (int it = 0; it < 4; ++it) {
      const int chunk = it*256 + tid;
      const int kv = chunk & 63;
      const int d0 = (chunk >> 6) * 8;
      uint4 raw = *(const uint4*)(vb + (size_t)(j*64 + kv)*NQKV + d0);
      const __hip_bfloat16* pv = (const __hip_bfloat16*)&raw;
#pragma unroll
      for (int t = 0; t < 8; ++t) Vt[(d0 + t)*VT_S + kv] = pv[t];
    }
    __syncthreads();

    // S = Q K^T
    f32x4 s[4] = {};
    const short* Kp = (const short*)Ks;
#pragma unroll
    for (int ks = 0; ks < 4; ++ks) {
      const int slot = ((ks*4 + q4) ^ sw) * 8;
#pragma unroll
      for (int nt = 0; nt < 4; ++nt) {
        bf16x8 bk = *(const bf16x8*)&Kp[(nt*16 + ln)*128 + slot];
        s[nt] = __builtin_amdgcn_mfma_f32_16x16x32_bf16(aq[ks], bk, s[nt], 0, 0, 0);
      }
    }

    // online softmax
    float p[4][4];
#pragma unroll
    for (int r = 0; r < 4; ++r) {
      float mx = mrow[r];
#pragma unroll
      for (int nt = 0; nt < 4; ++nt) {
        float v = s[nt][r] * sc;
        if (j == qt) {
          const int qrow = w*16 + q4*4 + r;
          const int kvc = nt*16 + ln;
          if (kvc > qrow) v = -1e30f;
        }
        p[r][nt] = v;
        mx = fmaxf(mx, v);
      }
#pragma unroll
      for (int d = 1; d < 16; d <<= 1) mx = fmaxf(mx, __shfl_xor(mx, d, 64));
      const float alpha = __expf(mrow[r] - mx);
      float rs = 0.f;
#pragma unroll
      for (int nt = 0; nt < 4; ++nt) { const float e = __expf(p[r][nt] - mx); p[r][nt] = e; rs += e; }
#pragma unroll
      for (int d = 1; d < 16; d <<= 1) rs += __shfl_xor(rs, d, 64);
      mrow[r] = mx;
      lrow[r] = lrow[r]*alpha + rs;
#pragma unroll
      for (int ni = 0; ni < 8; ++ni) o[ni][r] *= alpha;
    }

    // P -> wave-private LDS tile
    __hip_bfloat16* Pw = Ps[w];
#pragma unroll
    for (int r = 0; r < 4; ++r)
#pragma unroll
      for (int nt = 0; nt < 4; ++nt)
        Pw[(q4*4 + r)*PS_S + nt*16 + ln] = __float2bfloat16(p[r][nt]);

    // O += P V
    const short* Pp = (const short*)Ps[w];
    const short* Vp = (const short*)Vt;
#pragma unroll
    for (int ks = 0; ks < 2; ++ks) {
      bf16x8 ap = lds_read8_b64(&Pp[ln*PS_S + ks*32 + q4*8]);
#pragma unroll
      for (int ni = 0; ni < 8; ++ni) {
        bf16x8 bv = lds_read8_b64(&Vp[(ni*16 + ln)*VT_S + ks*32 + q4*8]);
        o[ni] = __builtin_amdgcn_mfma_f32_16x16x32_bf16(ap, bv, o[ni], 0, 0, 0);
      }
    }
  }

  // epilogue
  const int row0 = b*SEQ + qt*64 + w*16 + q4*4;
#pragma unroll
  for (int r = 0; r < 4; ++r) {
    const float inv = 1.f / lrow[r];
#pragma unroll
    for (int ni = 0; ni < 8; ++ni)
      out[(size_t)(row0 + r)*HIDDEN + h*HD + ni*16 + ln] = __float2bfloat16(o[ni][r] * inv);
  }
}

extern "C" void kernel_launch(void* const* d_in, const int* in_sizes, int n_in,
                              void* d_out, int out_size, void* d_ws, size_t ws_size,
                              hipStream_t stream) {
  (void)in_sizes; (void)n_in; (void)out_size; (void)ws_size;
  const float* x  = (const float*)d_in[0];
  const float* Wq = (const float*)d_in[2];
  const float* Aq = (const float*)d_in[3];
  const float* Bq = (const float*)d_in[4];
  const float* mq = (const float*)d_in[5];
  const float* Wk = (const float*)d_in[6];
  const float* Ak = (const float*)d_in[7];
  const float* Bk = (const float*)d_in[8];
  const float* mk = (const float*)d_in[9];
  const float* Wv = (const float*)d_in[10];
  const float* Av = (const float*)d_in[11];
  const float* Bv = (const float*)d_in[12];
  const float* mv = (const float*)d_in[13];
  const float* Wo = (const float*)d_in[14];
  const float* Ao = (const float*)d_in[15];
  const float* Bo = (const float*)d_in[16];
  const float* mo = (const float*)d_in[17];

  char* ws = (char*)d_ws;
  __hip_bfloat16* xbf = (__hip_bfloat16*)ws;                          // 32 MiB, reused as attn_out
  __hip_bfloat16* wd  = (__hip_bfloat16*)(ws + (size_t)33554432);     // 48 MiB, reused as Wd_o
  __hip_bfloat16* qkv = (__hip_bfloat16*)(ws + (size_t)83886080);     // 48 MiB

  cast_kernel<<<16384, 256, 0, stream>>>(x, (unsigned short*)xbf);
  wd_kernel<<<4096, 256, 0, stream>>>(Wq, Aq, Bq, mq, (unsigned short*)wd);
  wd_kernel<<<1024, 256, 0, stream>>>(Wk, Ak, Bk, mk, (unsigned short*)(wd + (size_t)4096*4096));
  wd_kernel<<<1024, 256, 0, stream>>>(Wv, Av, Bv, mv, (unsigned short*)(wd + (size_t)5120*4096));
  gemm_bt<__hip_bfloat16><<<dim3(48, 32), 256, 0, stream>>>(xbf, wd, qkv, MROWS, NQKV, HIDDEN);
  wd_kernel<<<4096, 256, 0, stream>>>(Wo, Ao, Bo, mo, (unsigned short*)wd);
  attn_kernel<<<2048, 256, 0, stream>>>(qkv, xbf);
  gemm_bt<float><<<dim3(32, 32), 256, 0, stream>>>(xbf, wd, (float*)d_out, MROWS, HIDDEN, HIDDEN);
}

// Round 4
// 819.083 us; speedup vs baseline: 1.6957x; 1.1000x over previous
//
#include <hip/hip_runtime.h>
#include <hip/hip_bf16.h>
#include <stdint.h>

#define HIDDEN 4096
#define RANK   8
#define SCALING 2.0f
#define EPS    1e-8f
#define SEQ    2048
#define BATCH  2
#define NH     32
#define NKVH   8
#define HD     128
#define MROWS  (BATCH*SEQ)   // 4096
#define NQKV   6144          // 4096 q | 1024 k | 1024 v

typedef __attribute__((ext_vector_type(8))) short bf16x8;
typedef __attribute__((ext_vector_type(4))) short bf16x4;
typedef __attribute__((ext_vector_type(4))) float f32x4;

__device__ __forceinline__ void gload_lds16(const void* g, void* lds) {
  __builtin_amdgcn_global_load_lds((__attribute__((address_space(1))) void*)g,
                                   (__attribute__((address_space(3))) void*)lds,
                                   16, 0, 0);
}

__device__ __forceinline__ unsigned short f2bf(float f) {
  __hip_bfloat16 h = __float2bfloat16(f);
  return *reinterpret_cast<unsigned short*>(&h);
}

__device__ __forceinline__ void store_c(float* p, float v) { *p = v; }
__device__ __forceinline__ void store_c(__hip_bfloat16* p, float v) { *p = __float2bfloat16(v); }

__device__ __forceinline__ bf16x8 lds_read8_b64(const short* p) {
  bf16x4 lo = *(const bf16x4*)p;
  bf16x4 hi = *(const bf16x4*)(p + 4);
  bf16x8 r;
  r[0]=lo[0]; r[1]=lo[1]; r[2]=lo[2]; r[3]=lo[3];
  r[4]=hi[0]; r[5]=hi[1]; r[6]=hi[2]; r[7]=hi[3];
  return r;
}

// ---------------- DoRA W_d row (device helper) ----------------
__device__ __forceinline__ void wd_row(const float* __restrict__ W, const float* __restrict__ A,
                                       const float* __restrict__ B, const float* __restrict__ m,
                                       unsigned short* __restrict__ out, int row, int tid,
                                       float* wsum) {
  float bl[RANK];
#pragma unroll
  for (int t = 0; t < RANK; ++t) bl[t] = SCALING * B[row*RANK + t];
  float ev[16];
  float ss = 0.f;
#pragma unroll
  for (int it = 0; it < 4; ++it) {
    const int j = it*1024 + tid*4;
    const float4 wv = *(const float4*)&W[(size_t)row*HIDDEN + j];
    float e0 = wv.x, e1 = wv.y, e2 = wv.z, e3 = wv.w;
#pragma unroll
    for (int t = 0; t < RANK; ++t) {
      const float4 av = *(const float4*)&A[t*HIDDEN + j];
      e0 += bl[t]*av.x; e1 += bl[t]*av.y; e2 += bl[t]*av.z; e3 += bl[t]*av.w;
    }
    ev[it*4+0]=e0; ev[it*4+1]=e1; ev[it*4+2]=e2; ev[it*4+3]=e3;
    ss += e0*e0 + e1*e1 + e2*e2 + e3*e3;
  }
#pragma unroll
  for (int off = 32; off > 0; off >>= 1) ss += __shfl_down(ss, off, 64);
  if ((tid & 63) == 0) wsum[tid >> 6] = ss;
  __syncthreads();
  const float norm = sqrtf(wsum[0]+wsum[1]+wsum[2]+wsum[3]);
  const float scl = m[row] / (norm + EPS);
#pragma unroll
  for (int it = 0; it < 4; ++it) {
    const int j = it*1024 + tid*4;
    ushort4 pk;
    pk.x = f2bf(ev[it*4+0]*scl); pk.y = f2bf(ev[it*4+1]*scl);
    pk.z = f2bf(ev[it*4+2]*scl); pk.w = f2bf(ev[it*4+3]*scl);
    *(ushort4*)&out[(size_t)row*HIDDEN + j] = pk;
  }
}

// ---------------- prep: cast x -> bf16 + all DoRA W_d in one launch ----------------
// block ranges: [0,16384) cast | [16384,+4096) wd_q | [+1024) wd_k | [+1024) wd_v | [+4096 opt) wd_o
__launch_bounds__(256)
__global__ void prep_kernel(const float* __restrict__ x, unsigned short* __restrict__ xbf,
                            const float* Wq, const float* Aq, const float* Bq, const float* mq, unsigned short* wdq,
                            const float* Wk, const float* Ak, const float* Bk, const float* mk, unsigned short* wdk,
                            const float* Wv, const float* Av, const float* Bv, const float* mv, unsigned short* wdv,
                            const float* Wo, const float* Ao, const float* Bo, const float* mo, unsigned short* wdo) {
  __shared__ float wsum[4];
  const int bid = blockIdx.x;
  const int tid = threadIdx.x;
  if (bid < 16384) {
    const size_t i = ((size_t)bid * 256 + tid) * 4;
    const float4 v = *(const float4*)&x[i];
    ushort4 pk;
    pk.x = f2bf(v.x); pk.y = f2bf(v.y); pk.z = f2bf(v.z); pk.w = f2bf(v.w);
    *(ushort4*)&xbf[i] = pk;
  } else if (bid < 20480) {
    wd_row(Wq, Aq, Bq, mq, wdq, bid - 16384, tid, wsum);
  } else if (bid < 21504) {
    wd_row(Wk, Ak, Bk, mk, wdk, bid - 20480, tid, wsum);
  } else if (bid < 22528) {
    wd_row(Wv, Av, Bv, mv, wdv, bid - 21504, tid, wsum);
  } else {
    wd_row(Wo, Ao, Bo, mo, wdo, bid - 22528, tid, wsum);
  }
}

__launch_bounds__(256)
__global__ void wd_kernel(const float* __restrict__ W, const float* __restrict__ A,
                          const float* __restrict__ B, const float* __restrict__ m,
                          unsigned short* __restrict__ out) {
  __shared__ float wsum[4];
  wd_row(W, A, B, m, out, blockIdx.x, threadIdx.x, wsum);
}

// ---------------- bf16 GEMM: C[M,N] = A[M,K] * B[N,K]^T ----------------
// m97 structure + XOR chunk swizzle (slot c^(r%8)); conflicts verified gone (r3).
template<typename CT>
__launch_bounds__(256)
__global__ void gemm_bt(const __hip_bfloat16* __restrict__ A,
                        const __hip_bfloat16* __restrict__ B,
                        CT* __restrict__ C, const int M, const int N, const int K) {
  __shared__ __hip_bfloat16 As[128*64];
  __shared__ __hip_bfloat16 Bs[128*64];
  const int tid = threadIdx.x;
  const int w = tid >> 6, l = tid & 63;
  const int tM = blockIdx.y * 128, tN = blockIdx.x * 128;
  const int wm = (w >> 1) * 64, wn = (w & 1) * 64;
  const int lr = l >> 3;
  const int lcs = ((l & 7) ^ lr) * 8;
  const int q4 = l >> 4;
  const int ln = l & 15;
  const int sw = ln & 7;
  f32x4 acc[4][4] = {};
  const __hip_bfloat16* Ab = A + (size_t)tM * K;
  const __hip_bfloat16* Bb = B + (size_t)tN * K;
  for (int k0 = 0; k0 < K; k0 += 64) {
    __syncthreads();
#pragma unroll
    for (int i = 0; i < 4; ++i) {
      const int rr = i*32 + w*8;
      gload_lds16(Ab + (size_t)(rr + lr)*K + (k0 + lcs), &As[rr*64]);
      gload_lds16(Bb + (size_t)(rr + lr)*K + (k0 + lcs), &Bs[rr*64]);
    }
    __syncthreads();
    const short* Ap = (const short*)As;
    const short* Bp = (const short*)Bs;
#pragma unroll
    for (int ks = 0; ks < 2; ++ks) {
      const int slot = ((ks*4 + q4) ^ sw) * 8;
      bf16x8 af[4], bff[4];
#pragma unroll
      for (int mi = 0; mi < 4; ++mi)
        af[mi] = *(const bf16x8*)&Ap[(wm + mi*16 + ln)*64 + slot];
#pragma unroll
      for (int ni = 0; ni < 4; ++ni)
        bff[ni] = *(const bf16x8*)&Bp[(wn + ni*16 + ln)*64 + slot];
#pragma unroll
      for (int mi = 0; mi < 4; ++mi)
#pragma unroll
        for (int ni = 0; ni < 4; ++ni)
          acc[mi][ni] = __builtin_amdgcn_mfma_f32_16x16x32_bf16(af[mi], bff[ni], acc[mi][ni], 0, 0, 0);
    }
  }
  const int r0 = tM + wm + q4*4;
  const int c0 = tN + wn + ln;
#pragma unroll
  for (int mi = 0; mi < 4; ++mi)
#pragma unroll
    for (int ni = 0; ni < 4; ++ni)
#pragma unroll
      for (int r = 0; r < 4; ++r)
        store_c(&C[(size_t)(r0 + mi*16 + r)*N + c0 + ni*16], acc[mi][ni][r]);
}

// ---------------- flash attention v2 (causal, GQA) ----------------
// Block = 128 q rows (two 64-row halves sharing staged K/V), 64 kv per iter.
// Transposed scores S^T = MFMA(K-frag, Q-frag): each lane owns one q row ->
// in-lane softmax reductions + 2 shfl (q4 dim). Wave w owns rows w*16..+15 of
// each half. LDS: Ks 16K + Vt 17K + Ps 2x per wave 17K = 50KB -> 3 blocks/CU.
#define VT_S 68
#define PS_S 68
__launch_bounds__(256, 3)
__global__ void attn_kernel(const __hip_bfloat16* __restrict__ qkv,
                            __hip_bfloat16* __restrict__ out) {
  const int bid = blockIdx.x;
  const int qt = 15 - (bid >> 6);      // big tiles first
  const int hb = bid & 63;
  const int h  = hb & 31;
  const int b  = hb >> 5;
  const int kvh = h >> 2;
  const int tid = threadIdx.x;
  const int w = tid >> 6, l = tid & 63;
  const int q4 = l >> 4;
  const int ln = l & 15;
  const int sw = ln & 7;

  __shared__ __hip_bfloat16 Ks[64*128];
  __shared__ __hip_bfloat16 Vt[128*VT_S];
  __shared__ __hip_bfloat16 Ps[4][2][16*PS_S];

  const __hip_bfloat16* kb = qkv + (size_t)(b*SEQ)*NQKV + HIDDEN + kvh*HD;
  const __hip_bfloat16* vb = qkv + (size_t)(b*SEQ)*NQKV + (HIDDEN+1024) + kvh*HD;

  const int Q0 = qt*128;

  // K staging swizzle (per-lane constant)
  const int krow = l >> 4;
  const int kchunk = ((l & 15) ^ krow ^ ((w & 1) << 2)) * 8;

  // V transpose assignment
  const int vc4 = (tid & 15) * 4;      // kv base (4 rows)
  const int vd0 = (tid >> 4) * 8;      // d base (8 cols)

  // Q fragments (B-operand layout): lane (q4,ln) -> q row (half)*64 + w*16+ln,
  // d = ks*32 + q4*8 .. +7
  bf16x8 aq[2][4];
#pragma unroll
  for (int hf = 0; hf < 2; ++hf) {
    const __hip_bfloat16* qr = qkv + (size_t)(b*SEQ + Q0 + hf*64 + w*16 + ln)*NQKV + h*HD;
#pragma unroll
    for (int ks = 0; ks < 4; ++ks) {
      uint4 raw = *(const uint4*)(qr + ks*32 + q4*8);
      aq[hf][ks] = *(const bf16x8*)&raw;
    }
  }

  f32x4 o[2][8] = {};
  float mx[2] = {-1e30f, -1e30f};
  float lsum[2] = {0.f, 0.f};
  const float sc = 0.08838834764831845f;  // 1/sqrt(128)
  const int qabs0 = Q0 + w*16 + ln;       // abs q row for half 0 (this lane)

  const int jmax = 2*qt + 1;
  for (int j = 0; j <= jmax; ++j) {
    const int do0 = (j <= 2*qt);
    __syncthreads();
    // stage K (64x128), swizzled DMA
#pragma unroll
    for (int i = 0; i < 4; ++i) {
      const int rr = i*16 + w*4;
      gload_lds16(kb + (size_t)(j*64 + rr + krow)*NQKV + kchunk, &Ks[rr*128]);
    }
    // stage V transposed via in-register 4x8 transpose -> 8x ds_write_b64
    {
      uint4 r0 = *(const uint4*)(vb + (size_t)(j*64 + vc4 + 0)*NQKV + vd0);
      uint4 r1 = *(const uint4*)(vb + (size_t)(j*64 + vc4 + 1)*NQKV + vd0);
      uint4 r2 = *(const uint4*)(vb + (size_t)(j*64 + vc4 + 2)*NQKV + vd0);
      uint4 r3 = *(const uint4*)(vb + (size_t)(j*64 + vc4 + 3)*NQKV + vd0);
      const unsigned short* p0 = (const unsigned short*)&r0;
      const unsigned short* p1 = (const unsigned short*)&r1;
      const unsigned short* p2 = (const unsigned short*)&r2;
      const unsigned short* p3 = (const unsigned short*)&r3;
#pragma unroll
      for (int t = 0; t < 8; ++t) {
        ushort4 pk; pk.x = p0[t]; pk.y = p1[t]; pk.z = p2[t]; pk.w = p3[t];
        *(ushort4*)&Vt[(vd0 + t)*VT_S + vc4] = pk;
      }
    }
    __syncthreads();

    // S^T = K Q^T : s[hf][nt] C-layout -> kv = nt*16+q4*4+r, q = ln
    f32x4 s[2][4] = {};
    const short* Kp = (const short*)Ks;
#pragma unroll
    for (int ks = 0; ks < 4; ++ks) {
      const int slot = ((ks*4 + q4) ^ sw) * 8;
#pragma unroll
      for (int nt = 0; nt < 4; ++nt) {
        bf16x8 bk = *(const bf16x8*)&Kp[(nt*16 + ln)*128 + slot];
        if (do0) s[0][nt] = __builtin_amdgcn_mfma_f32_16x16x32_bf16(bk, aq[0][ks], s[0][nt], 0, 0, 0);
        s[1][nt] = __builtin_amdgcn_mfma_f32_16x16x32_bf16(bk, aq[1][ks], s[1][nt], 0, 0, 0);
      }
    }

    // softmax per half (lane owns q row = hf*64 + w*16 + ln)
#pragma unroll
    for (int hf = 0; hf < 2; ++hf) {
      if (hf == 0 && !do0) continue;
      const int qabs = qabs0 + hf*64;
      // masking only on this half's diagonal tile
      if (j == 2*qt + hf) {
#pragma unroll
        for (int nt = 0; nt < 4; ++nt)
#pragma unroll
          for (int r = 0; r < 4; ++r) {
            const int kvabs = j*64 + nt*16 + q4*4 + r;
            if (kvabs > qabs) s[hf][nt][r] = -1e30f;
          }
      }
      float vmax = mx[hf];
#pragma unroll
      for (int nt = 0; nt < 4; ++nt)
#pragma unroll
        for (int r = 0; r < 4; ++r) vmax = fmaxf(vmax, s[hf][nt][r]);
      vmax = fmaxf(vmax, __shfl_xor(vmax, 16, 64));
      vmax = fmaxf(vmax, __shfl_xor(vmax, 32, 64));
      const float alpha = __expf((mx[hf] - vmax) * sc);
      float rs = 0.f;
#pragma unroll
      for (int nt = 0; nt < 4; ++nt)
#pragma unroll
        for (int r = 0; r < 4; ++r) {
          const float e = __expf((s[hf][nt][r] - vmax) * sc);
          s[hf][nt][r] = e; rs += e;
        }
      rs += __shfl_xor(rs, 16, 64);
      rs += __shfl_xor(rs, 32, 64);
      mx[hf] = vmax;
      lsum[hf] = lsum[hf]*alpha + rs;
      // rescale o (alpha broadcast to C-layout rows)
#pragma unroll
      for (int r = 0; r < 4; ++r) {
        const float ar = __shfl(alpha, q4*4 + r, 64);
#pragma unroll
        for (int ni = 0; ni < 8; ++ni) o[hf][ni][r] *= ar;
      }
      // write P[q][kv] rows: lane q=ln, kv = nt*16+q4*4..+3 -> b64
      __hip_bfloat16* Pw = Ps[w][hf];
#pragma unroll
      for (int nt = 0; nt < 4; ++nt) {
        ushort4 pk;
        pk.x = f2bf(s[hf][nt][0]); pk.y = f2bf(s[hf][nt][1]);
        pk.z = f2bf(s[hf][nt][2]); pk.w = f2bf(s[hf][nt][3]);
        *(ushort4*)&Pw[ln*PS_S + nt*16 + q4*4] = pk;
      }
    }

    // O += P V (V-frags read once, applied to both halves)
    const short* Vp = (const short*)Vt;
    const short* Pp0 = (const short*)Ps[w][0];
    const short* Pp1 = (const short*)Ps[w][1];
#pragma unroll
    for (int ks = 0; ks < 2; ++ks) {
      bf16x8 ap0 = lds_read8_b64(&Pp0[ln*PS_S + ks*32 + q4*8]);
      bf16x8 ap1 = lds_read8_b64(&Pp1[ln*PS_S + ks*32 + q4*8]);
#pragma unroll
      for (int ni = 0; ni < 8; ++ni) {
        bf16x8 bv = lds_read8_b64(&Vp[(ni*16 + ln)*VT_S + ks*32 + q4*8]);
        if (do0) o[0][ni] = __builtin_amdgcn_mfma_f32_16x16x32_bf16(ap0, bv, o[0][ni], 0, 0, 0);
        o[1][ni] = __builtin_amdgcn_mfma_f32_16x16x32_bf16(ap1, bv, o[1][ni], 0, 0, 0);
      }
    }
  }

  // epilogue
#pragma unroll
  for (int hf = 0; hf < 2; ++hf) {
    const int row0 = b*SEQ + Q0 + hf*64 + w*16 + q4*4;
#pragma unroll
    for (int r = 0; r < 4; ++r) {
      const float lr = __shfl(lsum[hf], q4*4 + r, 64);
      const float inv = 1.f / lr;
#pragma unroll
      for (int ni = 0; ni < 8; ++ni)
        out[(size_t)(row0 + r)*HIDDEN + h*HD + ni*16 + ln] = __float2bfloat16(o[hf][ni][r] * inv);
    }
  }
}

extern "C" void kernel_launch(void* const* d_in, const int* in_sizes, int n_in,
                              void* d_out, int out_size, void* d_ws, size_t ws_size,
                              hipStream_t stream) {
  (void)in_sizes; (void)n_in; (void)out_size;
  const float* x  = (const float*)d_in[0];
  const float* Wq = (const float*)d_in[2];
  const float* Aq = (const float*)d_in[3];
  const float* Bq = (const float*)d_in[4];
  const float* mq = (const float*)d_in[5];
  const float* Wk = (const float*)d_in[6];
  const float* Ak = (const float*)d_in[7];
  const float* Bk = (const float*)d_in[8];
  const float* mk = (const float*)d_in[9];
  const float* Wv = (const float*)d_in[10];
  const float* Av = (const float*)d_in[11];
  const float* Bv = (const float*)d_in[12];
  const float* mv = (const float*)d_in[13];
  const float* Wo = (const float*)d_in[14];
  const float* Ao = (const float*)d_in[15];
  const float* Bo = (const float*)d_in[16];
  const float* mo = (const float*)d_in[17];

  char* ws = (char*)d_ws;
  __hip_bfloat16* xbf = (__hip_bfloat16*)ws;                          // 32 MiB, reused as attn_out
  __hip_bfloat16* wd  = (__hip_bfloat16*)(ws + (size_t)33554432);     // 48 MiB
  __hip_bfloat16* qkv = (__hip_bfloat16*)(ws + (size_t)83886080);     // 48 MiB
  const bool big = ws_size >= (size_t)167772160;                      // 160 MiB
  __hip_bfloat16* wdo = big ? (__hip_bfloat16*)(ws + (size_t)134217728) : wd;

  prep_kernel<<<big ? 26624 : 22528, 256, 0, stream>>>(
      x, (unsigned short*)xbf,
      Wq, Aq, Bq, mq, (unsigned short*)wd,
      Wk, Ak, Bk, mk, (unsigned short*)(wd + (size_t)4096*4096),
      Wv, Av, Bv, mv, (unsigned short*)(wd + (size_t)5120*4096),
      Wo, Ao, Bo, mo, (unsigned short*)wdo);
  gemm_bt<__hip_bfloat16><<<dim3(48, 32), 256, 0, stream>>>(xbf, wd, qkv, MROWS, NQKV, HIDDEN);
  if (!big)
    wd_kernel<<<4096, 256, 0, stream>>>(Wo, Ao, Bo, mo, (unsigned short*)wdo);
  attn_kernel<<<1024, 256, 0, stream>>>(qkv, xbf);
  gemm_bt<float><<<dim3(32, 32), 256, 0, stream>>>(xbf, wdo, (float*)d_out, MROWS, HIDDEN, HIDDEN);
}